// Round 1
// baseline (276.990 us; speedup 1.0000x reference)
//
#include <hip/hip_runtime.h>

#define NBLOCKS 2048
#define NTHREADS 256

__global__ __launch_bounds__(NTHREADS) void l1_partial_kernel(
    const float4* __restrict__ a, const float4* __restrict__ b,
    float* __restrict__ partial, long n4) {
    long idx = (long)blockIdx.x * blockDim.x + threadIdx.x;
    long stride = (long)gridDim.x * blockDim.x;
    float acc = 0.0f;
    for (long i = idx; i < n4; i += stride) {
        float4 x = a[i];
        float4 y = b[i];
        acc += fabsf(x.x - y.x);
        acc += fabsf(x.y - y.y);
        acc += fabsf(x.z - y.z);
        acc += fabsf(x.w - y.w);
    }
    // wave-64 reduction
    #pragma unroll
    for (int off = 32; off > 0; off >>= 1)
        acc += __shfl_down(acc, off, 64);
    __shared__ float smem[NTHREADS / 64];
    int wave = threadIdx.x >> 6;
    int lane = threadIdx.x & 63;
    if (lane == 0) smem[wave] = acc;
    __syncthreads();
    if (threadIdx.x == 0) {
        float s = 0.0f;
        #pragma unroll
        for (int w = 0; w < NTHREADS / 64; ++w) s += smem[w];
        partial[blockIdx.x] = s;  // every block writes -> no stale-poison reads
    }
}

__global__ __launch_bounds__(NTHREADS) void l1_final_kernel(
    const float* __restrict__ partial, int nblocks,
    const float* __restrict__ a_tail, const float* __restrict__ b_tail,
    long tail_start, long n_total, float* __restrict__ out) {
    float acc = 0.0f;
    for (int i = threadIdx.x; i < nblocks; i += blockDim.x)
        acc += partial[i];
    // scalar tail (n not divisible by 4) — here n % 4 == 0 but keep it general
    for (long i = tail_start + threadIdx.x; i < n_total; i += blockDim.x)
        acc += fabsf(a_tail[i] - b_tail[i]);
    #pragma unroll
    for (int off = 32; off > 0; off >>= 1)
        acc += __shfl_down(acc, off, 64);
    __shared__ float smem[NTHREADS / 64];
    int wave = threadIdx.x >> 6;
    int lane = threadIdx.x & 63;
    if (lane == 0) smem[wave] = acc;
    __syncthreads();
    if (threadIdx.x == 0) {
        float s = 0.0f;
        #pragma unroll
        for (int w = 0; w < NTHREADS / 64; ++w) s += smem[w];
        out[0] = s / (float)n_total;
    }
}

extern "C" void kernel_launch(void* const* d_in, const int* in_sizes, int n_in,
                              void* d_out, int out_size, void* d_ws, size_t ws_size,
                              hipStream_t stream) {
    const float* yhat = (const float*)d_in[0];
    const float* y    = (const float*)d_in[1];
    float* out = (float*)d_out;
    float* partial = (float*)d_ws;  // NBLOCKS floats = 8 KB scratch

    long n = (long)in_sizes[0];
    long n4 = n / 4;
    long tail_start = n4 * 4;

    l1_partial_kernel<<<NBLOCKS, NTHREADS, 0, stream>>>(
        (const float4*)yhat, (const float4*)y, partial, n4);
    l1_final_kernel<<<1, NTHREADS, 0, stream>>>(
        partial, NBLOCKS, yhat, y, tail_start, n, out);
}

// Round 2
// 275.262 us; speedup vs baseline: 1.0063x; 1.0063x over previous
//
#include <hip/hip_runtime.h>

#define NBLOCKS 2048
#define NTHREADS 256

__global__ __launch_bounds__(NTHREADS) void l1_fused_kernel(
    const float4* __restrict__ a, const float4* __restrict__ b,
    const float* __restrict__ af, const float* __restrict__ bf,
    float* __restrict__ out, long n4, long n_total, float inv_n) {
    const long gid = (long)blockIdx.x * NTHREADS + threadIdx.x;
    const long stride = (long)NBLOCKS * NTHREADS;

    float acc0 = 0.f, acc1 = 0.f, acc2 = 0.f, acc3 = 0.f;
    long i = gid;
    // 4x unrolled: 8 independent 16B loads in flight before any use.
    for (; i + 3 * stride < n4; i += 4 * stride) {
        float4 x0 = a[i];
        float4 x1 = a[i + stride];
        float4 x2 = a[i + 2 * stride];
        float4 x3 = a[i + 3 * stride];
        float4 y0 = b[i];
        float4 y1 = b[i + stride];
        float4 y2 = b[i + 2 * stride];
        float4 y3 = b[i + 3 * stride];
        acc0 += fabsf(x0.x - y0.x) + fabsf(x0.y - y0.y) +
                fabsf(x0.z - y0.z) + fabsf(x0.w - y0.w);
        acc1 += fabsf(x1.x - y1.x) + fabsf(x1.y - y1.y) +
                fabsf(x1.z - y1.z) + fabsf(x1.w - y1.w);
        acc2 += fabsf(x2.x - y2.x) + fabsf(x2.y - y2.y) +
                fabsf(x2.z - y2.z) + fabsf(x2.w - y2.w);
        acc3 += fabsf(x3.x - y3.x) + fabsf(x3.y - y3.y) +
                fabsf(x3.z - y3.z) + fabsf(x3.w - y3.w);
    }
    for (; i < n4; i += stride) {
        float4 x = a[i];
        float4 y = b[i];
        acc0 += fabsf(x.x - y.x) + fabsf(x.y - y.y) +
                fabsf(x.z - y.z) + fabsf(x.w - y.w);
    }
    // scalar tail (n % 4 != 0 safety; no-op for this shape)
    for (long e = n4 * 4 + gid; e < n_total; e += stride)
        acc0 += fabsf(af[e] - bf[e]);

    float acc = (acc0 + acc1) + (acc2 + acc3);

    // wave-64 reduction
    #pragma unroll
    for (int off = 32; off > 0; off >>= 1)
        acc += __shfl_down(acc, off, 64);

    __shared__ float smem[NTHREADS / 64];
    int wave = threadIdx.x >> 6;
    int lane = threadIdx.x & 63;
    if (lane == 0) smem[wave] = acc;
    __syncthreads();
    if (threadIdx.x == 0) {
        float s = 0.f;
        #pragma unroll
        for (int w = 0; w < NTHREADS / 64; ++w) s += smem[w];
        atomicAdd(out, s * inv_n);  // device-scope by default; ~2048 adds total
    }
}

extern "C" void kernel_launch(void* const* d_in, const int* in_sizes, int n_in,
                              void* d_out, int out_size, void* d_ws, size_t ws_size,
                              hipStream_t stream) {
    const float* yhat = (const float*)d_in[0];
    const float* y    = (const float*)d_in[1];
    float* out = (float*)d_out;

    long n = (long)in_sizes[0];
    long n4 = n / 4;
    float inv_n = 1.0f / (float)n;

    // d_out is poisoned 0xAA before every launch — zero the accumulator first.
    hipMemsetAsync(out, 0, sizeof(float), stream);
    l1_fused_kernel<<<NBLOCKS, NTHREADS, 0, stream>>>(
        (const float4*)yhat, (const float4*)y, yhat, y, out, n4, n, inv_n);
}